// Round 2
// baseline (15125.992 us; speedup 1.0000x reference)
//
#include <hip/hip_runtime.h>
#include <hip/hip_bf16.h>

// Gru2: L=2, HS=512, IN=512, B=64, S=1024. Inputs/outputs are FLOAT32
// (reference uses jnp.float32; round-1 NaN = f32 misread as bf16).
// Facts: layers independent (both read x_t); r-gate unused; 4-term gate
// collapses to Wc = W1[g]*W2 + dW1[g]*dW2 (rows [z;n]), same for Uc.
// Persistent kernel: 64 WGs = 2 layers x 8 row-slices x 4 batch-groups(16).
// Each WG combines its weight slices to bf16 MFMA A-frags in registers at
// init (no workspace for weights). h state carried as bf16 in a 2-slot
// ping-pong buffer; per-step sync per 8-WG domain via agent-scope flags.

#define HS 512
#define IN_DIM 512
#define BATCH 64
#define SEQ 1024
#define NB 16
#define NSLICE 8
#define NDOM 8

typedef __attribute__((ext_vector_type(8))) short bf16x8;
typedef __attribute__((ext_vector_type(4))) float f32x4;
typedef unsigned long long u64;
typedef unsigned short ushort_t;

__device__ __forceinline__ unsigned short f2bf(float f) {
  unsigned u = __float_as_uint(f);
  u += 0x7FFFu + ((u >> 16) & 1u);
  return (unsigned short)(u >> 16);
}
__device__ __forceinline__ float bf2f(unsigned short s) {
  return __uint_as_float(((unsigned)s) << 16);
}

// ---- prep: init h slot0 (f32 -> bf16) and zero flags ----
__global__ void gru_prep(const float* __restrict__ h0,
                         ushort_t* __restrict__ hbuf,
                         unsigned* __restrict__ flags) {
  unsigned tid = blockIdx.x * 256u + threadIdx.x;
  if (tid < 2u * BATCH * HS) hbuf[tid] = f2bf(h0[tid]);  // slot0, [l][b][k]
  if (tid < NDOM * (SEQ + 1)) flags[tid] = 0u;
}

// ---- main persistent recurrence ----
__global__ __launch_bounds__(256, 1) void gru_main(
    const float* __restrict__ x, float* __restrict__ out,
    const float* __restrict__ W1, const float* __restrict__ W2,
    const float* __restrict__ U1, const float* __restrict__ U2,
    const float* __restrict__ dW1, const float* __restrict__ dW2,
    const float* __restrict__ dU1, const float* __restrict__ dU2,
    const float* __restrict__ b1, const float* __restrict__ b2,
    ushort_t* __restrict__ hbuf, unsigned* __restrict__ flags) {
  const int bid    = blockIdx.x;   // 0..63
  const int domain = bid & 7;      // all 8 slices of a domain share bid%8 (same XCD)
  const int slice  = bid >> 3;     // 0..7 row slice
  const int layer  = domain & 1;
  const int bg     = domain >> 1;  // 0..3
  const int bo     = bg * NB;
  const int tid    = threadIdx.x;
  const int lane   = tid & 63;
  const int wave   = tid >> 6;
  const int quad   = lane >> 4;
  const int ln     = lane & 15;
  const int hw     = slice * 64 + wave * 16;  // first h-row of this wave

  // --- init: combine weights into register-resident bf16 A-frags ---
  // A-frag layout: A[m=lane&15][k=quad*8+j]
  const float w1z = W1[layer*3+1], w1n = W1[layer*3+2];
  const float dw1z = dW1[layer*3+1], dw1n = dW1[layer*3+2];
  const float u1z = U1[layer*3+1], u1n = U1[layer*3+2];
  const float du1z = dU1[layer*3+1], du1n = dU1[layer*3+2];
  const int hrow = hw + ln;
  const float* W2r  = W2  + ((size_t)layer*HS + hrow) * IN_DIM;
  const float* dW2r = dW2 + ((size_t)layer*HS + hrow) * IN_DIM;
  const float* U2r  = U2  + ((size_t)layer*HS + hrow) * HS;
  const float* dU2r = dU2 + ((size_t)layer*HS + hrow) * HS;

  bf16x8 uf[2][16], wf[2][16];
#pragma unroll
  for (int kc = 0; kc < 16; ++kc) {
    const int off = kc*32 + quad*8;
#pragma unroll
    for (int i = 0; i < 8; ++i) {
      float w2 = W2r[off+i], dw2 = dW2r[off+i];
      float u2 = U2r[off+i], du2 = dU2r[off+i];
      wf[0][kc][i] = (short)f2bf(w1z*w2 + dw1z*dw2);
      wf[1][kc][i] = (short)f2bf(w1n*w2 + dw1n*dw2);
      uf[0][kc][i] = (short)f2bf(u1z*u2 + du1z*du2);
      uf[1][kc][i] = (short)f2bf(u1n*u2 + du1n*du2);
    }
  }
  float bz[4], bn[4];
#pragma unroll
  for (int r = 0; r < 4; ++r) {
    const int row = hw + quad*4 + r;
    bz[r] = b1[layer*1536 + 512  + row] + b2[layer*1536 + 512  + row];
    bn[r] = b1[layer*1536 + 1024 + row] + b2[layer*1536 + 1024 + row];
  }

  const int b_lane = bo + ln;  // this lane's batch (B-frag col, D col)
  const float* xb = x + (size_t)b_lane * SEQ * IN_DIM;
  unsigned* flag = flags + domain * (SEQ + 1);
  const size_t slotsz = (size_t)2 * BATCH * HS;
  ushort_t* hl = hbuf + (size_t)layer * BATCH * HS;

  for (int t = 0; t < SEQ; ++t) {
    f32x4 accz = {0.f, 0.f, 0.f, 0.f};
    f32x4 accn = {0.f, 0.f, 0.f, 0.f};
    // x-projection first: h-independent, overlaps flag wait
    const float* xt = xb + (size_t)t * IN_DIM;
#pragma unroll
    for (int kc = 0; kc < 16; ++kc) {
      union { f32x4 v[2]; float f[8]; } xu;
      xu.v[0] = *(const f32x4*)(xt + kc*32 + quad*8);
      xu.v[1] = *(const f32x4*)(xt + kc*32 + quad*8 + 4);
      bf16x8 xv;
#pragma unroll
      for (int i = 0; i < 8; ++i) xv[i] = (short)f2bf(xu.f[i]);
      accz = __builtin_amdgcn_mfma_f32_16x16x32_bf16(wf[0][kc], xv, accz, 0, 0, 0);
      accn = __builtin_amdgcn_mfma_f32_16x16x32_bf16(wf[1][kc], xv, accn, 0, 0, 0);
    }
    if (t > 0) {
      if (tid == 0) {
        while (__hip_atomic_load(flag + t, __ATOMIC_RELAXED, __HIP_MEMORY_SCOPE_AGENT) < NSLICE)
          __builtin_amdgcn_s_sleep(1);
      }
      __syncthreads();
    }
    const ushort_t* hsrc = hl + (size_t)(t & 1) * slotsz + (size_t)b_lane * HS;
#pragma unroll
    for (int kc = 0; kc < 16; ++kc) {
      const u64* hp = (const u64*)(hsrc + kc*32 + quad*8);
      union { u64 q[2]; bf16x8 v; } hu;
      hu.q[0] = __hip_atomic_load(hp,     __ATOMIC_RELAXED, __HIP_MEMORY_SCOPE_AGENT);
      hu.q[1] = __hip_atomic_load(hp + 1, __ATOMIC_RELAXED, __HIP_MEMORY_SCOPE_AGENT);
      accz = __builtin_amdgcn_mfma_f32_16x16x32_bf16(uf[0][kc], hu.v, accz, 0, 0, 0);
      accn = __builtin_amdgcn_mfma_f32_16x16x32_bf16(uf[1][kc], hu.v, accn, 0, 0, 0);
    }
    // epilogue: D row quad*4+r -> h-row hw+quad*4+r ; D col ln -> batch b_lane
    u64 hprev = __hip_atomic_load((const u64*)(hsrc + hw + quad*4),
                                  __ATOMIC_RELAXED, __HIP_MEMORY_SCOPE_AGENT);
    u64 packed = 0;
    f32x4 hnew;
#pragma unroll
    for (int r = 0; r < 4; ++r) {
      float gz = accz[r] + bz[r];
      float gn = accn[r] + bn[r];
      float z = 1.f / (1.f + __expf(-gz));
      float n = tanhf(gn);
      float hp = bf2f((unsigned short)(hprev >> (16 * r)));
      float hn = (1.f - z) * n + z * hp;
      hnew[r] = hn;
      packed |= ((u64)f2bf(hn)) << (16 * r);
    }
    ushort_t* hdst = hl + (size_t)((t + 1) & 1) * slotsz + (size_t)b_lane * HS + hw + quad*4;
    __hip_atomic_store((u64*)hdst, packed, __ATOMIC_RELAXED, __HIP_MEMORY_SCOPE_AGENT);
    if (layer == 1)
      *(f32x4*)(out + ((size_t)b_lane * SEQ + t) * HS + hw + quad*4) = hnew;
    if (t == SEQ - 1)
      *(f32x4*)(out + (size_t)BATCH * SEQ * HS
                + ((size_t)layer * BATCH + b_lane) * HS + hw + quad*4) = hnew;
    __syncthreads();  // drains each wave's stores (vmcnt 0) before flag publish
    if (tid == 0 && t + 1 < SEQ)
      __hip_atomic_fetch_add(flag + (t + 1), 1u, __ATOMIC_RELEASE, __HIP_MEMORY_SCOPE_AGENT);
  }
}

extern "C" void kernel_launch(void* const* d_in, const int* in_sizes, int n_in,
                              void* d_out, int out_size, void* d_ws, size_t ws_size,
                              hipStream_t stream) {
  const float* x   = (const float*)d_in[0];
  const float* h0  = (const float*)d_in[1];
  const float* W1  = (const float*)d_in[2];
  const float* W2  = (const float*)d_in[3];
  const float* U1  = (const float*)d_in[4];
  const float* U2  = (const float*)d_in[5];
  const float* dW1 = (const float*)d_in[6];
  const float* dW2 = (const float*)d_in[7];
  const float* dU1 = (const float*)d_in[8];
  const float* dU2 = (const float*)d_in[9];
  const float* b1  = (const float*)d_in[10];
  const float* b2  = (const float*)d_in[11];

  char* ws = (char*)d_ws;
  ushort_t* hbuf  = (ushort_t*)ws;                    // 256 KiB (2 slots x 2L x 64 x 512 bf16)
  unsigned* flags = (unsigned*)(ws + 262144);         // ~33 KiB

  gru_prep<<<256, 256, 0, stream>>>(h0, hbuf, flags);
  gru_main<<<64, 256, 0, stream>>>(x, (float*)d_out,
                                   W1, W2, U1, U2, dW1, dW2, dU1, dU2, b1, b2,
                                   hbuf, flags);
}

// Round 3
// 7233.604 us; speedup vs baseline: 2.0911x; 2.0911x over previous
//
#include <hip/hip_runtime.h>

// Gru2: L=2, HS=512, IN=512, B=64, S=1024, f32 in/out.
// Layers independent; r-gate unused; gates collapse to Wc=W1*W2+dW1*dW2,
// Uc=U1*U2+dU1*dU2, rows [z;n]. 64 persistent WGs = 2L x 8 row-slices x
// 4 batch-groups(16). Weights live in VGPR/AGPR as MFMA A-frags.
// Round-3 change: relaxed-only sync (no agent-release -> no buffer_wbl2),
// per-wave flag polling, x staged to LDS via global_load_lds double-buffer.

#define HS 512
#define IN_DIM 512
#define BATCH 64
#define SEQ 1024
#define NB 16
#define NDOM 8
#define LDS_ROW 516  // floats per staged batch row (2064B = 2KB + 16B pad)

typedef __attribute__((ext_vector_type(8))) short bf16x8;
typedef __attribute__((ext_vector_type(4))) float f32x4;
typedef unsigned long long u64;
typedef unsigned int u32;
typedef unsigned short ushort_t;

__device__ __forceinline__ ushort_t f2bf(float f) {  // RNE
  u32 u = __float_as_uint(f);
  u += 0x7FFFu + ((u >> 16) & 1u);
  return (ushort_t)(u >> 16);
}
__device__ __forceinline__ float bf2f(ushort_t s) {
  return __uint_as_float(((u32)s) << 16);
}

// ---- prep: h slot0 (f32->bf16), zero flags ----
__global__ void gru_prep(const float* __restrict__ h0,
                         ushort_t* __restrict__ hbuf,
                         u32* __restrict__ flags) {
  u32 tid = blockIdx.x * 256u + threadIdx.x;
  if (tid < 2u * BATCH * HS) hbuf[tid] = f2bf(h0[tid]);       // [l][b][k]
  if (tid < NDOM * (SEQ + 1) * 8u) flags[tid] = 0u;
}

__global__ __launch_bounds__(256, 1) void gru_main(
    const float* __restrict__ x, float* __restrict__ out,
    const float* __restrict__ W1, const float* __restrict__ W2,
    const float* __restrict__ U1, const float* __restrict__ U2,
    const float* __restrict__ dW1, const float* __restrict__ dW2,
    const float* __restrict__ dU1, const float* __restrict__ dU2,
    const float* __restrict__ b1, const float* __restrict__ b2,
    ushort_t* __restrict__ hbuf, u32* __restrict__ flags) {
  __shared__ float xlds[2][NB * LDS_ROW];   // 2 x 33KB double buffer

  const int bid    = blockIdx.x;       // 0..63
  const int domain = bid & 7;
  const int slice  = bid >> 3;         // 0..7
  const int layer  = domain & 1;
  const int bg     = domain >> 1;
  const int bo     = bg * NB;
  const int tid    = threadIdx.x;
  const int lane   = tid & 63;
  const int wave   = tid >> 6;
  const int quad   = lane >> 4;
  const int ln     = lane & 15;
  const int hw     = slice * 64 + wave * 16;

  // --- combine weights into register-resident bf16 A-frags (A[m=ln][k=quad*8+j]) ---
  const float w1z = W1[layer*3+1], w1n = W1[layer*3+2];
  const float dw1z = dW1[layer*3+1], dw1n = dW1[layer*3+2];
  const float u1z = U1[layer*3+1], u1n = U1[layer*3+2];
  const float du1z = dU1[layer*3+1], du1n = dU1[layer*3+2];
  const int hrow = hw + ln;
  const float* W2r  = W2  + ((size_t)layer*HS + hrow) * IN_DIM;
  const float* dW2r = dW2 + ((size_t)layer*HS + hrow) * IN_DIM;
  const float* U2r  = U2  + ((size_t)layer*HS + hrow) * HS;
  const float* dU2r = dU2 + ((size_t)layer*HS + hrow) * HS;

  bf16x8 uf[2][16], wf[2][16];
#pragma unroll
  for (int kc = 0; kc < 16; ++kc) {
    const int off = kc*32 + quad*8;
#pragma unroll
    for (int i = 0; i < 8; ++i) {
      float w2 = W2r[off+i], dw2 = dW2r[off+i];
      float u2 = U2r[off+i], du2 = dU2r[off+i];
      wf[0][kc][i] = (short)f2bf(w1z*w2 + dw1z*dw2);
      wf[1][kc][i] = (short)f2bf(w1n*w2 + dw1n*dw2);
      uf[0][kc][i] = (short)f2bf(u1z*u2 + du1z*du2);
      uf[1][kc][i] = (short)f2bf(u1n*u2 + du1n*du2);
    }
  }
  float bz[4], bn[4];
#pragma unroll
  for (int r = 0; r < 4; ++r) {
    const int row = hw + quad*4 + r;
    bz[r] = b1[layer*1536 + 512  + row] + b2[layer*1536 + 512  + row];
    bn[r] = b1[layer*1536 + 1024 + row] + b2[layer*1536 + 1024 + row];
  }

  const int b_lane = bo + ln;
  const size_t slotsz = (size_t)2 * BATCH * HS;
  ushort_t* hl = hbuf + (size_t)layer * BATCH * HS;
  u32* const flagbase = flags + (size_t)domain * (SEQ + 1) * 8;

  const u64 omask = 1ULL << ((slice & 1) * 32);   // own WG's flag word (barrier-guaranteed)
  const u64 own0 = (slice >> 1) == 0 ? omask : 0;
  const u64 own1 = (slice >> 1) == 1 ? omask : 0;
  const u64 own2 = (slice >> 1) == 2 ? omask : 0;
  const u64 own3 = (slice >> 1) == 3 ? omask : 0;

  // --- stage x[0]: each wave loads 4 batches x 2 chunks of 1KB ---
#pragma unroll
  for (int i = 0; i < 8; ++i) {
    int bi = wave * 4 + (i >> 1), ch = i & 1;
    const float* g = x + ((size_t)(bo + bi) * SEQ) * IN_DIM + ch * 256 + lane * 4;
    __builtin_amdgcn_global_load_lds(
        (const __attribute__((address_space(1))) void*)g,
        (__attribute__((address_space(3))) void*)&xlds[0][bi * LDS_ROW + ch * 256],
        16, 0, 0);
  }
  asm volatile("s_waitcnt vmcnt(0)" ::: "memory");
  __syncthreads();

  for (int t = 0; t < SEQ; ++t) {
    // prefetch x[t+1] into the other LDS buffer (fire-and-forget)
    if (t + 1 < SEQ) {
#pragma unroll
      for (int i = 0; i < 8; ++i) {
        int bi = wave * 4 + (i >> 1), ch = i & 1;
        const float* g = x + ((size_t)(bo + bi) * SEQ + (t + 1)) * IN_DIM + ch * 256 + lane * 4;
        __builtin_amdgcn_global_load_lds(
            (const __attribute__((address_space(1))) void*)g,
            (__attribute__((address_space(3))) void*)&xlds[(t + 1) & 1][bi * LDS_ROW + ch * 256],
            16, 0, 0);
      }
    }
    // x-projection (h-independent; overlaps producer lag)
    f32x4 accz = {0.f,0.f,0.f,0.f}, accn = {0.f,0.f,0.f,0.f};
    const float* xrow = &xlds[t & 1][ln * LDS_ROW];
#pragma unroll
    for (int kc = 0; kc < 16; ++kc) {
      f32x4 a = *(const f32x4*)(xrow + kc*32 + quad*8);
      f32x4 b = *(const f32x4*)(xrow + kc*32 + quad*8 + 4);
      union { u32 u[4]; bf16x8 v; } xv;   // truncation cvt (err << bf16 h noise)
      xv.u[0] = (__float_as_uint(a[1]) & 0xFFFF0000u) | (__float_as_uint(a[0]) >> 16);
      xv.u[1] = (__float_as_uint(a[3]) & 0xFFFF0000u) | (__float_as_uint(a[2]) >> 16);
      xv.u[2] = (__float_as_uint(b[1]) & 0xFFFF0000u) | (__float_as_uint(b[0]) >> 16);
      xv.u[3] = (__float_as_uint(b[3]) & 0xFFFF0000u) | (__float_as_uint(b[2]) >> 16);
      accz = __builtin_amdgcn_mfma_f32_16x16x32_bf16(wf[0][kc], xv.v, accz, 0, 0, 0);
      accn = __builtin_amdgcn_mfma_f32_16x16x32_bf16(wf[1][kc], xv.v, accn, 0, 0, 0);
    }
    // wait for h[t]: per-wave relaxed poll of 8 per-WG flag words
    if (t > 0) {
      const u64* fp = (const u64*)(flagbase + (size_t)t * 8);
      for (;;) {
        u64 f0 = __hip_atomic_load(fp + 0, __ATOMIC_RELAXED, __HIP_MEMORY_SCOPE_SYSTEM);
        u64 f1 = __hip_atomic_load(fp + 1, __ATOMIC_RELAXED, __HIP_MEMORY_SCOPE_SYSTEM);
        u64 f2 = __hip_atomic_load(fp + 2, __ATOMIC_RELAXED, __HIP_MEMORY_SCOPE_SYSTEM);
        u64 f3 = __hip_atomic_load(fp + 3, __ATOMIC_RELAXED, __HIP_MEMORY_SCOPE_SYSTEM);
        u64 all = (f0 | own0) & (f1 | own1) & (f2 | own2) & (f3 | own3);
        if (all == 0x0000000100000001ULL) break;
        __builtin_amdgcn_s_sleep(1);
      }
    }
    // recurrent matvec
    const ushort_t* hsrc = hl + (size_t)(t & 1) * slotsz + (size_t)b_lane * HS;
#pragma unroll
    for (int kc = 0; kc < 16; ++kc) {
      const u64* hp = (const u64*)(hsrc + kc*32 + quad*8);
      union { u64 q[2]; bf16x8 v; } hu;
      hu.q[0] = __hip_atomic_load(hp,     __ATOMIC_RELAXED, __HIP_MEMORY_SCOPE_SYSTEM);
      hu.q[1] = __hip_atomic_load(hp + 1, __ATOMIC_RELAXED, __HIP_MEMORY_SCOPE_SYSTEM);
      accz = __builtin_amdgcn_mfma_f32_16x16x32_bf16(uf[0][kc], hu.v, accz, 0, 0, 0);
      accn = __builtin_amdgcn_mfma_f32_16x16x32_bf16(uf[1][kc], hu.v, accn, 0, 0, 0);
    }
    u64 hprev = __hip_atomic_load((const u64*)(hsrc + hw + quad*4),
                                  __ATOMIC_RELAXED, __HIP_MEMORY_SCOPE_SYSTEM);
    // epilogue: D row=quad*4+r -> h-row hw+quad*4+r ; D col=ln -> batch b_lane
    u64 packed = 0;
    f32x4 hnew;
#pragma unroll
    for (int r = 0; r < 4; ++r) {
      float gz = accz[r] + bz[r];
      float gn = accn[r] + bn[r];
      float z  = 1.f / (1.f + __expf(-gz));
      float e2 = __expf(2.f * gn);
      float n  = (e2 - 1.f) / (e2 + 1.f);
      float hp = bf2f((ushort_t)(hprev >> (16 * r)));
      float hn = (1.f - z) * n + z * hp;
      hnew[r] = hn;
      packed |= ((u64)f2bf(hn)) << (16 * r);
    }
    __hip_atomic_store((u64*)(hl + (size_t)((t + 1) & 1) * slotsz
                              + (size_t)b_lane * HS + hw + quad*4),
                       packed, __ATOMIC_RELAXED, __HIP_MEMORY_SCOPE_SYSTEM);
    if (layer == 1)
      *(f32x4*)(out + ((size_t)b_lane * SEQ + t) * HS + hw + quad*4) = hnew;
    if (t == SEQ - 1)
      *(f32x4*)(out + (size_t)BATCH * SEQ * HS
                + ((size_t)layer * BATCH + b_lane) * HS + hw + quad*4) = hnew;
    // manual release: drain this wave's stores (and x prefetch), converge WG,
    // then ONE relaxed flag store. No RMW, no buffer_wbl2.
    asm volatile("s_waitcnt vmcnt(0)" ::: "memory");
    __syncthreads();
    if (tid == 0)
      __hip_atomic_store(flagbase + (size_t)(t + 1) * 8 + slice, 1u,
                         __ATOMIC_RELAXED, __HIP_MEMORY_SCOPE_SYSTEM);
  }
}

extern "C" void kernel_launch(void* const* d_in, const int* in_sizes, int n_in,
                              void* d_out, int out_size, void* d_ws, size_t ws_size,
                              hipStream_t stream) {
  const float* x   = (const float*)d_in[0];
  const float* h0  = (const float*)d_in[1];
  const float* W1  = (const float*)d_in[2];
  const float* W2  = (const float*)d_in[3];
  const float* U1  = (const float*)d_in[4];
  const float* U2  = (const float*)d_in[5];
  const float* dW1 = (const float*)d_in[6];
  const float* dW2 = (const float*)d_in[7];
  const float* dU1 = (const float*)d_in[8];
  const float* dU2 = (const float*)d_in[9];
  const float* b1  = (const float*)d_in[10];
  const float* b2  = (const float*)d_in[11];

  char* ws = (char*)d_ws;
  ushort_t* hbuf  = (ushort_t*)ws;                 // 256 KiB: 2 slots x [l][b][k] bf16
  u32*      flags = (u32*)(ws + 262144);           // 8 dom x 1025 x 8 words = 256.25 KiB

  gru_prep<<<257, 256, 0, stream>>>(h0, hbuf, flags);
  gru_main<<<64, 256, 0, stream>>>(x, (float*)d_out,
                                   W1, W2, U1, U2, dW1, dW2, dU1, dU2, b1, b2,
                                   hbuf, flags);
}